// Round 8
// baseline (131.237 us; speedup 1.0000x reference)
//
#include <hip/hip_runtime.h>

#define LQ 1024
#define DIM 128
#define NT 512
#define QT 32

typedef __attribute__((ext_vector_type(8))) short bf16x8;
typedef __attribute__((ext_vector_type(4))) float f32x4;
typedef __attribute__((ext_vector_type(2))) unsigned u32x2;

__device__ __forceinline__ unsigned pk2(float a, float b) {
  unsigned short ux = __builtin_bit_cast(unsigned short, (__bf16)a);
  unsigned short uy = __builtin_bit_cast(unsigned short, (__bf16)b);
  return (unsigned)ux | ((unsigned)uy << 16);
}
__device__ __forceinline__ bf16x8 pack8(f32x4 a, f32x4 b) {
  union { unsigned u[4]; bf16x8 v; } r;
  r.u[0] = pk2(a[0], a[1]); r.u[1] = pk2(a[2], a[3]);
  r.u[2] = pk2(b[0], b[1]); r.u[3] = pk2(b[2], b[3]);
  return r.v;
}

// ---------------- prepass: K fp32->bf16 copy; V fp32 -> bf16 transposed [d][k]
__global__ __launch_bounds__(NT)
void prep_kv(const float* __restrict__ Kp, const float* __restrict__ Vp,
             unsigned short* __restrict__ Kb, unsigned short* __restrict__ VT)
{
  __shared__ __align__(16) char lds[32768];
  const int t = (int)threadIdx.x;
  const int bid = (int)blockIdx.x;            // 256 blocks
  const int logical = (bid & 7) * 32 + (bid >> 3);  // XCD-chunked (matches main)
  const int b = logical >> 3;                 // batch
  const int o = logical & 7;                  // k-octant (128 rows)
  const size_t boff = (size_t)b * (LQ * DIM);

  { // K convert-copy rows [o*128, o*128+128)
    const float* src = Kp + boff + (size_t)o * 128 * DIM;
    unsigned short* dst = Kb + boff + (size_t)o * 128 * DIM;
    #pragma unroll
    for (int j = 0; j < 8; ++j) {
      int off = j * 2048 + t * 4;
      f32x4 v = __builtin_nontemporal_load((const f32x4*)(src + off));
      u32x2 p; p[0] = pk2(v[0], v[1]); p[1] = pk2(v[2], v[3]);
      *(u32x2*)(dst + off) = p;
    }
  }
  { // V transpose via swizzled LDS: rows [o*128..+128) -> VT[d][o*128+k]
    const float* src = Vp + boff + (size_t)o * 128 * DIM;
    #pragma unroll
    for (int i = 0; i < 8; ++i) {
      int kr = i * 16 + (t >> 5);
      int d4 = t & 31;
      f32x4 v = __builtin_nontemporal_load(
          (const f32x4*)(src + (size_t)kr * DIM + d4 * 4));
      #pragma unroll
      for (int dd = 0; dd < 4; ++dd) {
        int d = d4 * 4 + dd;
        int byt = (d * 256 + kr * 2) ^ ((d & 7) << 4);
        *(unsigned short*)(lds + byt) =
            __builtin_bit_cast(unsigned short, (__bf16)v[dd]);
      }
    }
    __syncthreads();
    #pragma unroll
    for (int j = 0; j < 4; ++j) {
      int d = j * 32 + (t >> 4);
      int k4 = t & 15;
      int byt = (d * 256 + k4 * 16) ^ ((d & 7) << 4);
      f32x4 x = *(const f32x4*)(lds + byt);
      *(f32x4*)(VT + boff + (size_t)d * LQ + o * 128 + k4 * 8) = x;
    }
  }
}

// ---------------- main kernel: QT=32, 2 q-groups share all K/V loads.
// G is consumed in PHASE 2 via w = exp((e^S * g) * l1i): the multiply by g
// commutes past the l1 barrier, so G's ~700cy L3 latency hides under the
// 64-transcendental exp shadow instead of sitting in phase 3's chain.
template<bool PRE>
__global__ __launch_bounds__(NT, 4)
void dsma_kernel(const float* __restrict__ Qp, const float* __restrict__ Kf,
                 const float* __restrict__ Vf,
                 const unsigned short* __restrict__ Kb,
                 const unsigned short* __restrict__ VT,
                 const float* __restrict__ Sp, const float* __restrict__ Gp,
                 float* __restrict__ Op)
{
  __shared__ __align__(16) char smem[65536 + 2048];
  char*  Wlds = smem;                           // W [32][1024] bf16, swizzled
  float* red0 = (float*)(smem + 65536);         // [2][8][16] : l1
  float* red1 = (float*)(smem + 65536 + 1024);  // [2][8][16] : l2

  const int tid  = (int)threadIdx.x;
  const int lane = tid & 63;
  const int wid  = tid >> 6;
  const int g4   = lane >> 4;
  const int ll   = lane & 15;
  const int bid  = (int)blockIdx.x;
  // XCD-chunked bijective swizzle: 1024 blocks, XCD x owns batches [4x,4x+4)
  const int logical = (bid & 7) * 128 + (bid >> 3);
  const int b     = logical >> 5;
  const int qbase = (logical & 31) * QT;
  const int cb0   = wid * 128;

  const float scale = Sp[0];
  const float* Qb = Qp + ((size_t)b * LQ + qbase) * DIM;
  const float* Gb = Gp + ((size_t)b * LQ + qbase) * (size_t)LQ;

  // Q fragments for both q-groups (rows ll and 16+ll), pre-scaled
  bf16x8 qf0[4], qf1[4];
  #pragma unroll
  for (int dc = 0; dc < 4; ++dc) {
    const float* qp0 = Qb + ll * DIM + g4 * 8 + dc * 32;
    const float* qp1 = Qb + (16 + ll) * DIM + g4 * 8 + dc * 32;
    f32x4 a0 = *(const f32x4*)qp0;       f32x4 c0 = *(const f32x4*)(qp0 + 4);
    f32x4 a1 = *(const f32x4*)qp1;       f32x4 c1 = *(const f32x4*)(qp1 + 4);
    a0 *= scale; c0 *= scale; a1 *= scale; c1 *= scale;
    qf0[dc] = pack8(a0, c0);  qf1[dc] = pack8(a1, c1);
  }

  // Phase 1: S^T via mfma(K, Q); each K-tile feeds BOTH q-groups.
  // S0[s][r] = score[k=cb0+s*16+g4*4+r][q=ll]; S1 same for q=16+ll group.
  f32x4 S0[8], S1[8];
  #pragma unroll
  for (int s = 0; s < 8; ++s) {
    S0[s][0]=0.f; S0[s][1]=0.f; S0[s][2]=0.f; S0[s][3]=0.f;
    S1[s][0]=0.f; S1[s][1]=0.f; S1[s][2]=0.f; S1[s][3]=0.f;
  }
  if constexpr (PRE) {
    const unsigned short* Kbb = Kb + (size_t)b * LQ * DIM;
    bf16x8 ktA[4], ktB[4];
    auto kloadt = [&](bf16x8* t, int s) {
      const unsigned short* kp = Kbb + (size_t)(cb0 + s * 16 + ll) * DIM + g4 * 8;
      t[0] = *(const bf16x8*)(kp);
      t[1] = *(const bf16x8*)(kp + 32);
      t[2] = *(const bf16x8*)(kp + 64);
      t[3] = *(const bf16x8*)(kp + 96);
    };
    auto kuset = [&](const bf16x8* t, int s) {
      #pragma unroll
      for (int dc = 0; dc < 4; ++dc) {
        S0[s] = __builtin_amdgcn_mfma_f32_16x16x32_bf16(t[dc], qf0[dc], S0[s], 0, 0, 0);
        S1[s] = __builtin_amdgcn_mfma_f32_16x16x32_bf16(t[dc], qf1[dc], S1[s], 0, 0, 0);
      }
    };
    kloadt(ktA, 0);
    #pragma unroll
    for (int s = 0; s < 8; s += 2) {
      if (s + 1 < 8) kloadt(ktB, s + 1);
      kuset(ktA, s);
      if (s + 2 < 8) kloadt(ktA, s + 2);
      if (s + 1 < 8) kuset(ktB, s + 1);
    }
  } else {
    const float* Kbf = Kf + (size_t)b * LQ * DIM;
    #pragma unroll
    for (int s = 0; s < 8; ++s) {
      const float* kp = Kbf + (size_t)(cb0 + s * 16 + ll) * DIM + g4 * 8;
      #pragma unroll
      for (int dc = 0; dc < 4; ++dc) {
        f32x4 a = *(const f32x4*)(kp + dc * 32);
        f32x4 c = *(const f32x4*)(kp + dc * 32 + 4);
        bf16x8 kf = pack8(a, c);
        S0[s] = __builtin_amdgcn_mfma_f32_16x16x32_bf16(kf, qf0[dc], S0[s], 0, 0, 0);
        S1[s] = __builtin_amdgcn_mfma_f32_16x16x32_bf16(kf, qf1[dc], S1[s], 0, 0, 0);
      }
    }
  }

  // G prefetch group 0 (qf regs die above; compiler can reuse for gpre).
  f32x4 gpre[8];
  {
    const float* gp = Gb + (size_t)ll * LQ + cb0;
    #pragma unroll
    for (int s = 0; s < 8; ++s)
      gpre[s] = __builtin_nontemporal_load((const f32x4*)(gp + s * 16 + g4 * 4));
  }

  // Phase 2: exp + l1 partial + fold G in (u = e^S * g), both groups.
  float lsum0 = 0.f, lsum1 = 0.f;
  #pragma unroll
  for (int s = 0; s < 8; ++s) {       // exp shadow covers g0 arrival
    #pragma unroll
    for (int r = 0; r < 4; ++r) { float e = __expf(S0[s][r]); lsum0 += e; S0[s][r] = e; }
  }
  #pragma unroll
  for (int s = 0; s < 8; ++s) { S0[s] *= gpre[s]; }
  { // issue g1; resolves under S1's exp chain
    const float* gp1 = Gb + (size_t)(16 + ll) * LQ + cb0;
    #pragma unroll
    for (int s = 0; s < 8; ++s)
      gpre[s] = __builtin_nontemporal_load((const f32x4*)(gp1 + s * 16 + g4 * 4));
  }
  #pragma unroll
  for (int s = 0; s < 8; ++s) {
    #pragma unroll
    for (int r = 0; r < 4; ++r) { float e = __expf(S1[s][r]); lsum1 += e; S1[s][r] = e; }
  }
  #pragma unroll
  for (int s = 0; s < 8; ++s) { S1[s] *= gpre[s]; }

  lsum0 += __shfl_xor(lsum0, 16, 64);  lsum0 += __shfl_xor(lsum0, 32, 64);
  lsum1 += __shfl_xor(lsum1, 16, 64);  lsum1 += __shfl_xor(lsum1, 32, 64);
  if (lane < 16) {
    red0[wid * 16 + lane]       = lsum0;
    red0[128 + wid * 16 + lane] = lsum1;
  }
  __syncthreads();
  float l1i0 = 0.f, l1i1 = 0.f;
  #pragma unroll
  for (int w = 0; w < 8; ++w) {
    l1i0 += red0[w * 16 + ll];
    l1i1 += red0[128 + w * 16 + ll];
  }
  l1i0 = 1.0f / l1i0;  l1i1 = 1.0f / l1i1;

  // Phase 3: pure VALU now. w = exp(u * l1i), pack, swizzled LDS write.
  float l2p0 = 0.f, l2p1 = 0.f;
  #pragma unroll
  for (int s = 0; s < 8; ++s) {
    float w0 = __expf(S0[s][0] * l1i0);
    float w1 = __expf(S0[s][1] * l1i0);
    float w2 = __expf(S0[s][2] * l1i0);
    float w3 = __expf(S0[s][3] * l1i0);
    l2p0 += (w0 + w1) + (w2 + w3);
    u32x2 pk; pk[0] = pk2(w0, w1); pk[1] = pk2(w2, w3);
    int byt = ll * 2048 + (cb0 + s * 16 + g4 * 4) * 2;
    byt ^= (ll & 7) << 4;
    *(u32x2*)(Wlds + byt) = pk;
  }
  #pragma unroll
  for (int s = 0; s < 8; ++s) {
    float w0 = __expf(S1[s][0] * l1i1);
    float w1 = __expf(S1[s][1] * l1i1);
    float w2 = __expf(S1[s][2] * l1i1);
    float w3 = __expf(S1[s][3] * l1i1);
    l2p1 += (w0 + w1) + (w2 + w3);
    u32x2 pk; pk[0] = pk2(w0, w1); pk[1] = pk2(w2, w3);
    int byt = (16 + ll) * 2048 + (cb0 + s * 16 + g4 * 4) * 2;
    byt ^= (ll & 7) << 4;   // (16+ll)&7 == ll&7
    *(u32x2*)(Wlds + byt) = pk;
  }

  // V ring prefetch (first 8): independent of W; hides under the l2
  // shuffle/LDS-write/barrier below.
  const int dsub = wid * 16;
  const unsigned short* vrow = VT + (size_t)b * LQ * DIM +
                               (size_t)(dsub + ll) * LQ;
  auto vld = [&](int f) { return *(const bf16x8*)(vrow + f * 32 + g4 * 8); };
  bf16x8 r0, r1, r2, r3, r4, r5, r6, r7;
  if constexpr (PRE) {
    r0 = vld(0); r1 = vld(1); r2 = vld(2); r3 = vld(3);
    r4 = vld(4); r5 = vld(5); r6 = vld(6); r7 = vld(7);
  }

  l2p0 += __shfl_xor(l2p0, 16, 64);  l2p0 += __shfl_xor(l2p0, 32, 64);
  l2p1 += __shfl_xor(l2p1, 16, 64);  l2p1 += __shfl_xor(l2p1, 32, 64);
  if (lane < 16) {
    red1[wid * 16 + lane]       = l2p0;
    red1[128 + wid * 16 + lane] = l2p1;
  }
  __syncthreads();   // W complete + l2 partials complete

  float l2i0[4], l2i1[4];
  #pragma unroll
  for (int r = 0; r < 4; ++r) {
    float t0 = 0.f, t1 = 0.f;
    #pragma unroll
    for (int w = 0; w < 8; ++w) {
      t0 += red1[w * 16 + g4 * 4 + r];
      t1 += red1[128 + w * 16 + g4 * 4 + r];
    }
    l2i0[r] = 1.0f / t0;  l2i1[r] = 1.0f / t1;
  }

  // Phase 4: O = W V; wave owns d-subtile [wid*16,+16). Each V fragment
  // feeds BOTH q-groups' MFMAs. 8-deep V ring.
  f32x4 acc0 = {0.f, 0.f, 0.f, 0.f}, acc1 = {0.f, 0.f, 0.f, 0.f};
  auto wuse2 = [&](bf16x8 vf, int ff) {
    int ab0 = ll * 2048 + (ff * 32 + g4 * 8) * 2;        ab0 ^= (ll & 7) << 4;
    int ab1 = (16 + ll) * 2048 + (ff * 32 + g4 * 8) * 2; ab1 ^= (ll & 7) << 4;
    bf16x8 af0 = *(const bf16x8*)(Wlds + ab0);
    bf16x8 af1 = *(const bf16x8*)(Wlds + ab1);
    acc0 = __builtin_amdgcn_mfma_f32_16x16x32_bf16(af0, vf, acc0, 0, 0, 0);
    acc1 = __builtin_amdgcn_mfma_f32_16x16x32_bf16(af1, vf, acc1, 0, 0, 0);
  };
  if constexpr (PRE) {
    #pragma unroll
    for (int f = 0; f < 32; f += 8) {
      wuse2(r0, f);     if (f + 8  < 32) r0 = vld(f + 8);
      wuse2(r1, f + 1); if (f + 9  < 32) r1 = vld(f + 9);
      wuse2(r2, f + 2); if (f + 10 < 32) r2 = vld(f + 10);
      wuse2(r3, f + 3); if (f + 11 < 32) r3 = vld(f + 11);
      wuse2(r4, f + 4); if (f + 12 < 32) r4 = vld(f + 12);
      wuse2(r5, f + 5); if (f + 13 < 32) r5 = vld(f + 13);
      wuse2(r6, f + 6); if (f + 14 < 32) r6 = vld(f + 14);
      wuse2(r7, f + 7); if (f + 15 < 32) r7 = vld(f + 15);
    }
  } else {
    const float* vcol = Vf + (size_t)b * LQ * DIM + dsub + ll;
    #pragma unroll
    for (int f = 0; f < 32; ++f) {
      const float* vp = vcol + (size_t)(f * 32 + g4 * 8) * DIM;
      union { unsigned u[4]; bf16x8 v; } vf;
      vf.u[0] = pk2(vp[0 * DIM], vp[1 * DIM]);
      vf.u[1] = pk2(vp[2 * DIM], vp[3 * DIM]);
      vf.u[2] = pk2(vp[4 * DIM], vp[5 * DIM]);
      vf.u[3] = pk2(vp[6 * DIM], vp[7 * DIM]);
      wuse2(vf.v, f);
    }
  }

  // Epilogue: normalize, non-temporal store (write-once stream)
  float* op = Op + ((size_t)b * LQ + qbase) * DIM + dsub + ll;
  #pragma unroll
  for (int r = 0; r < 4; ++r) {
    __builtin_nontemporal_store(acc0[r] * l2i0[r],
                                op + (size_t)(g4 * 4 + r) * DIM);
    __builtin_nontemporal_store(acc1[r] * l2i1[r],
                                op + (size_t)(16 + g4 * 4 + r) * DIM);
  }
}

extern "C" void kernel_launch(void* const* d_in, const int* in_sizes, int n_in,
                              void* d_out, int out_size, void* d_ws, size_t ws_size,
                              hipStream_t stream) {
  const float* Q = (const float*)d_in[0];
  const float* K = (const float*)d_in[1];
  const float* V = (const float*)d_in[2];
  const float* s = (const float*)d_in[3];
  const float* G = (const float*)d_in[4];
  float* O = (float*)d_out;

  const size_t elems = (size_t)32 * LQ * DIM;           // per tensor
  const size_t need  = elems * 2 /*bf16*/ * 2 /*K+VT*/; // 16 MB
  if (ws_size >= need) {
    unsigned short* Kb = (unsigned short*)d_ws;
    unsigned short* VT = Kb + elems;
    prep_kv<<<256, NT, 0, stream>>>(K, V, Kb, VT);
    dsma_kernel<true><<<1024, NT, 0, stream>>>(Q, K, V, Kb, VT, s, G, O);
  } else {
    dsma_kernel<false><<<1024, NT, 0, stream>>>(Q, K, V, nullptr, nullptr, s, G, O);
  }
}

// Round 9
// 94.237 us; speedup vs baseline: 1.3926x; 1.3926x over previous
//
#include <hip/hip_runtime.h>

#define LQ 1024
#define DIM 128
#define NT 512
#define QT 32

typedef __attribute__((ext_vector_type(8))) short bf16x8;
typedef __attribute__((ext_vector_type(4))) float f32x4;
typedef __attribute__((ext_vector_type(2))) unsigned u32x2;

__device__ __forceinline__ unsigned pk2(float a, float b) {
  unsigned short ux = __builtin_bit_cast(unsigned short, (__bf16)a);
  unsigned short uy = __builtin_bit_cast(unsigned short, (__bf16)b);
  return (unsigned)ux | ((unsigned)uy << 16);
}
__device__ __forceinline__ bf16x8 pack8(f32x4 a, f32x4 b) {
  union { unsigned u[4]; bf16x8 v; } r;
  r.u[0] = pk2(a[0], a[1]); r.u[1] = pk2(a[2], a[3]);
  r.u[2] = pk2(b[0], b[1]); r.u[3] = pk2(b[2], b[3]);
  return r.v;
}

// ---------------- prepass: K fp32->bf16 copy; V fp32 -> bf16 transposed [d][k]
__global__ __launch_bounds__(NT)
void prep_kv(const float* __restrict__ Kp, const float* __restrict__ Vp,
             unsigned short* __restrict__ Kb, unsigned short* __restrict__ VT)
{
  __shared__ __align__(16) char lds[32768];
  const int t = (int)threadIdx.x;
  const int bid = (int)blockIdx.x;            // 256 blocks
  const int logical = (bid & 7) * 32 + (bid >> 3);  // XCD-chunked (matches main)
  const int b = logical >> 3;                 // batch
  const int o = logical & 7;                  // k-octant (128 rows)
  const size_t boff = (size_t)b * (LQ * DIM);

  { // K convert-copy rows [o*128, o*128+128)
    const float* src = Kp + boff + (size_t)o * 128 * DIM;
    unsigned short* dst = Kb + boff + (size_t)o * 128 * DIM;
    #pragma unroll
    for (int j = 0; j < 8; ++j) {
      int off = j * 2048 + t * 4;
      f32x4 v = __builtin_nontemporal_load((const f32x4*)(src + off));
      u32x2 p; p[0] = pk2(v[0], v[1]); p[1] = pk2(v[2], v[3]);
      *(u32x2*)(dst + off) = p;
    }
  }
  { // V transpose via swizzled LDS: rows [o*128..+128) -> VT[d][o*128+k]
    const float* src = Vp + boff + (size_t)o * 128 * DIM;
    #pragma unroll
    for (int i = 0; i < 8; ++i) {
      int kr = i * 16 + (t >> 5);
      int d4 = t & 31;
      f32x4 v = __builtin_nontemporal_load(
          (const f32x4*)(src + (size_t)kr * DIM + d4 * 4));
      #pragma unroll
      for (int dd = 0; dd < 4; ++dd) {
        int d = d4 * 4 + dd;
        int byt = (d * 256 + kr * 2) ^ ((d & 7) << 4);
        *(unsigned short*)(lds + byt) =
            __builtin_bit_cast(unsigned short, (__bf16)v[dd]);
      }
    }
    __syncthreads();
    #pragma unroll
    for (int j = 0; j < 4; ++j) {
      int d = j * 32 + (t >> 4);
      int k4 = t & 15;
      int byt = (d * 256 + k4 * 16) ^ ((d & 7) << 4);
      f32x4 x = *(const f32x4*)(lds + byt);
      *(f32x4*)(VT + boff + (size_t)d * LQ + o * 128 + k4 * 8) = x;
    }
  }
}

// ---------------- main kernel: QT=32, 2 q-groups share all K/V loads.
// Phase-1 K path uses global_load_lds (zero-VGPR staging, 2 chunks ahead,
// counted vmcnt, NO barriers -- each wave stages/reads only its own rows).
// LDS region X (64KB) = K-staging dbuf during phase 1, W afterwards.
template<bool PRE>
__global__ __launch_bounds__(NT, 4)
void dsma_kernel(const float* __restrict__ Qp, const float* __restrict__ Kf,
                 const float* __restrict__ Vf,
                 const unsigned short* __restrict__ Kb,
                 const unsigned short* __restrict__ VT,
                 const float* __restrict__ Sp, const float* __restrict__ Gp,
                 float* __restrict__ Op)
{
  __shared__ __align__(16) char smem[65536 + 2048];
  char*  Wlds = smem;                           // region X: K dbuf -> W [32][1024]
  float* red0 = (float*)(smem + 65536);         // [2][8][16] : l1
  float* red1 = (float*)(smem + 65536 + 1024);  // [2][8][16] : l2

  const int tid  = (int)threadIdx.x;
  const int lane = tid & 63;
  const int wid  = tid >> 6;
  const int g4   = lane >> 4;
  const int ll   = lane & 15;
  const int bid  = (int)blockIdx.x;
  // XCD-chunked bijective swizzle: 1024 blocks, XCD x owns batches [4x,4x+4)
  const int logical = (bid & 7) * 128 + (bid >> 3);
  const int b     = logical >> 5;
  const int qbase = (logical & 31) * QT;
  const int cb0   = wid * 128;

  const float scale = Sp[0];
  const float* Qb = Qp + ((size_t)b * LQ + qbase) * DIM;
  const float* Gb = Gp + ((size_t)b * LQ + qbase) * (size_t)LQ;

  // Q fragments for both q-groups (rows ll and 16+ll), pre-scaled
  bf16x8 qf0[4], qf1[4];
  #pragma unroll
  for (int dc = 0; dc < 4; ++dc) {
    const float* qp0 = Qb + ll * DIM + g4 * 8 + dc * 32;
    const float* qp1 = Qb + (16 + ll) * DIM + g4 * 8 + dc * 32;
    f32x4 a0 = *(const f32x4*)qp0;       f32x4 c0 = *(const f32x4*)(qp0 + 4);
    f32x4 a1 = *(const f32x4*)qp1;       f32x4 c1 = *(const f32x4*)(qp1 + 4);
    a0 *= scale; c0 *= scale; a1 *= scale; c1 *= scale;
    qf0[dc] = pack8(a0, c0);  qf1[dc] = pack8(a1, c1);
  }

  // Phase 1: S^T via mfma(K, Q); each K-tile feeds BOTH q-groups.
  // S0[s][r] = score[k=cb0+s*16+g4*4+r][q=ll]; S1 same for q=16+ll group.
  f32x4 S0[8], S1[8];
  #pragma unroll
  for (int s = 0; s < 8; ++s) {
    S0[s][0]=0.f; S0[s][1]=0.f; S0[s][2]=0.f; S0[s][3]=0.f;
    S1[s][0]=0.f; S1[s][1]=0.f; S1[s][2]=0.f; S1[s][3]=0.f;
  }
  if constexpr (PRE) {
    const unsigned short* Kbb = Kb + (size_t)b * LQ * DIM;
    // Stage chunk c (this wave's 16 K-rows, 4KB) into dbuf half (c&1).
    // LDS dest is linear (HW: base + lane*16); the XOR swizzle is applied
    // to the per-lane GLOBAL source (m173 pattern) and re-applied on read.
    auto kstage = [&](int c) {
      char* base = smem + ((c & 1) * 32768) + wid * 4096;
      #pragma unroll
      for (int i = 0; i < 4; ++i) {
        int j   = i * 4 + (lane >> 4);          // local row 0..15
        int s16 = lane & 15;                    // 16B slot within row
        int gr  = cb0 + c * 16 + j;             // global k-row
        const unsigned short* gp =
            Kbb + (size_t)gr * DIM + ((s16 ^ (j & 7)) * 8);
        __builtin_amdgcn_global_load_lds(
            (const __attribute__((address_space(1))) void*)gp,
            (__attribute__((address_space(3))) void*)(base + i * 1024),
            16, 0, 0);
      }
    };
    kstage(0); kstage(1);
    #pragma unroll
    for (int c = 0; c < 8; ++c) {
      if (c < 6) {
        kstage(c + 2);
        asm volatile("s_waitcnt vmcnt(8)" ::: "memory");
      } else if (c == 6) {
        asm volatile("s_waitcnt vmcnt(4)" ::: "memory");
      } else {
        asm volatile("s_waitcnt vmcnt(0)" ::: "memory");
      }
      __builtin_amdgcn_sched_barrier(0);
      const char* rb = smem + ((c & 1) * 32768) + wid * 4096;
      #pragma unroll
      for (int dc = 0; dc < 4; ++dc) {
        int rbyt = ll * 256 + ((((dc * 4 + g4) * 16)) ^ ((ll & 7) << 4));
        bf16x8 kf = *(const bf16x8*)(rb + rbyt);
        S0[c] = __builtin_amdgcn_mfma_f32_16x16x32_bf16(kf, qf0[dc], S0[c], 0, 0, 0);
        S1[c] = __builtin_amdgcn_mfma_f32_16x16x32_bf16(kf, qf1[dc], S1[c], 0, 0, 0);
      }
    }
  } else {
    const float* Kbf = Kf + (size_t)b * LQ * DIM;
    #pragma unroll
    for (int s = 0; s < 8; ++s) {
      const float* kp = Kbf + (size_t)(cb0 + s * 16 + ll) * DIM + g4 * 8;
      #pragma unroll
      for (int dc = 0; dc < 4; ++dc) {
        f32x4 a = *(const f32x4*)(kp + dc * 32);
        f32x4 c = *(const f32x4*)(kp + dc * 32 + 4);
        bf16x8 kf = pack8(a, c);
        S0[s] = __builtin_amdgcn_mfma_f32_16x16x32_bf16(kf, qf0[dc], S0[s], 0, 0, 0);
        S1[s] = __builtin_amdgcn_mfma_f32_16x16x32_bf16(kf, qf1[dc], S1[s], 0, 0, 0);
      }
    }
  }

  // G prefetch for group 0 (rows qbase+ll): resolves under phase 2.
  f32x4 gpre[8];
  {
    const float* gp = Gb + (size_t)ll * LQ + cb0;
    #pragma unroll
    for (int s = 0; s < 8; ++s)
      gpre[s] = __builtin_nontemporal_load((const f32x4*)(gp + s * 16 + g4 * 4));
  }

  // Phase 2: softmax1 denominators for both groups (no max-sub; ~N(0,1)).
  float lsum0 = 0.f, lsum1 = 0.f;
  #pragma unroll
  for (int s = 0; s < 8; ++s) {
    #pragma unroll
    for (int r = 0; r < 4; ++r) {
      float e0 = __expf(S0[s][r]);  S0[s][r] = e0;  lsum0 += e0;
      float e1 = __expf(S1[s][r]);  S1[s][r] = e1;  lsum1 += e1;
    }
  }
  lsum0 += __shfl_xor(lsum0, 16, 64);  lsum0 += __shfl_xor(lsum0, 32, 64);
  lsum1 += __shfl_xor(lsum1, 16, 64);  lsum1 += __shfl_xor(lsum1, 32, 64);
  if (lane < 16) {
    red0[wid * 16 + lane]       = lsum0;
    red0[128 + wid * 16 + lane] = lsum1;
  }
  __syncthreads();   // also: ALL waves past phase-1 LDS reads -> W may reuse X
  float l1i0 = 0.f, l1i1 = 0.f;
  #pragma unroll
  for (int w = 0; w < 8; ++w) {
    l1i0 += red0[w * 16 + ll];
    l1i1 += red0[128 + w * 16 + ll];
  }
  l1i0 = 1.0f / l1i0;  l1i1 = 1.0f / l1i1;

  // Phase 3a: group 0 -> W rows [0,16); as each gpre[s] is consumed, its
  // register is reloaded with the group-1 G value (stagger keeps regs <=128).
  const float* gp1 = Gb + (size_t)(16 + ll) * LQ + cb0;
  float l2p0 = 0.f, l2p1 = 0.f;
  #pragma unroll
  for (int s = 0; s < 8; ++s) {
    f32x4 g = gpre[s];
    gpre[s] = __builtin_nontemporal_load((const f32x4*)(gp1 + s * 16 + g4 * 4));
    float w0 = __expf(S0[s][0] * l1i0 * g[0]);
    float w1 = __expf(S0[s][1] * l1i0 * g[1]);
    float w2 = __expf(S0[s][2] * l1i0 * g[2]);
    float w3 = __expf(S0[s][3] * l1i0 * g[3]);
    l2p0 += (w0 + w1) + (w2 + w3);
    u32x2 pk; pk[0] = pk2(w0, w1); pk[1] = pk2(w2, w3);
    int byt = ll * 2048 + (cb0 + s * 16 + g4 * 4) * 2;
    byt ^= (ll & 7) << 4;
    *(u32x2*)(Wlds + byt) = pk;
  }
  // Phase 3b: group 1 -> W rows [16,32)
  #pragma unroll
  for (int s = 0; s < 8; ++s) {
    f32x4 g = gpre[s];
    float w0 = __expf(S1[s][0] * l1i1 * g[0]);
    float w1 = __expf(S1[s][1] * l1i1 * g[1]);
    float w2 = __expf(S1[s][2] * l1i1 * g[2]);
    float w3 = __expf(S1[s][3] * l1i1 * g[3]);
    l2p1 += (w0 + w1) + (w2 + w3);
    u32x2 pk; pk[0] = pk2(w0, w1); pk[1] = pk2(w2, w3);
    int byt = (16 + ll) * 2048 + (cb0 + s * 16 + g4 * 4) * 2;
    byt ^= (ll & 7) << 4;   // (16+ll)&7 == ll&7
    *(u32x2*)(Wlds + byt) = pk;
  }
  l2p0 += __shfl_xor(l2p0, 16, 64);  l2p0 += __shfl_xor(l2p0, 32, 64);
  l2p1 += __shfl_xor(l2p1, 16, 64);  l2p1 += __shfl_xor(l2p1, 32, 64);
  if (lane < 16) {
    red1[wid * 16 + lane]       = l2p0;
    red1[128 + wid * 16 + lane] = l2p1;
  }
  __syncthreads();   // W complete + l2 partials complete

  float l2i0[4], l2i1[4];
  #pragma unroll
  for (int r = 0; r < 4; ++r) {
    float t0 = 0.f, t1 = 0.f;
    #pragma unroll
    for (int w = 0; w < 8; ++w) {
      t0 += red1[w * 16 + g4 * 4 + r];
      t1 += red1[128 + w * 16 + g4 * 4 + r];
    }
    l2i0[r] = 1.0f / t0;  l2i1[r] = 1.0f / t1;
  }

  // Phase 4: O = W V; wave owns d-subtile [wid*16,+16). Each V fragment
  // feeds BOTH q-groups' MFMAs. 4-deep V ring.
  f32x4 acc0 = {0.f, 0.f, 0.f, 0.f}, acc1 = {0.f, 0.f, 0.f, 0.f};
  const int dsub = wid * 16;
  auto wuse2 = [&](bf16x8 vf, int ff) {
    int ab0 = ll * 2048 + (ff * 32 + g4 * 8) * 2;        ab0 ^= (ll & 7) << 4;
    int ab1 = (16 + ll) * 2048 + (ff * 32 + g4 * 8) * 2; ab1 ^= (ll & 7) << 4;
    bf16x8 af0 = *(const bf16x8*)(Wlds + ab0);
    bf16x8 af1 = *(const bf16x8*)(Wlds + ab1);
    acc0 = __builtin_amdgcn_mfma_f32_16x16x32_bf16(af0, vf, acc0, 0, 0, 0);
    acc1 = __builtin_amdgcn_mfma_f32_16x16x32_bf16(af1, vf, acc1, 0, 0, 0);
  };
  if constexpr (PRE) {
    const unsigned short* vrow = VT + (size_t)b * LQ * DIM +
                                 (size_t)(dsub + ll) * LQ;
    auto vld = [&](int f) { return *(const bf16x8*)(vrow + f * 32 + g4 * 8); };
    bf16x8 r0 = vld(0), r1 = vld(1), r2 = vld(2), r3 = vld(3);
    #pragma unroll
    for (int f = 0; f < 32; f += 4) {
      wuse2(r0, f);     if (f + 4 < 32) r0 = vld(f + 4);
      wuse2(r1, f + 1); if (f + 5 < 32) r1 = vld(f + 5);
      wuse2(r2, f + 2); if (f + 6 < 32) r2 = vld(f + 6);
      wuse2(r3, f + 3); if (f + 7 < 32) r3 = vld(f + 7);
    }
  } else {
    const float* vcol = Vf + (size_t)b * LQ * DIM + dsub + ll;
    #pragma unroll
    for (int f = 0; f < 32; ++f) {
      const float* vp = vcol + (size_t)(f * 32 + g4 * 8) * DIM;
      union { unsigned u[4]; bf16x8 v; } vf;
      vf.u[0] = pk2(vp[0 * DIM], vp[1 * DIM]);
      vf.u[1] = pk2(vp[2 * DIM], vp[3 * DIM]);
      vf.u[2] = pk2(vp[4 * DIM], vp[5 * DIM]);
      vf.u[3] = pk2(vp[6 * DIM], vp[7 * DIM]);
      wuse2(vf.v, f);
    }
  }

  // Epilogue: normalize, non-temporal store (write-once stream)
  float* op = Op + ((size_t)b * LQ + qbase) * DIM + dsub + ll;
  #pragma unroll
  for (int r = 0; r < 4; ++r) {
    __builtin_nontemporal_store(acc0[r] * l2i0[r],
                                op + (size_t)(g4 * 4 + r) * DIM);
    __builtin_nontemporal_store(acc1[r] * l2i1[r],
                                op + (size_t)(16 + g4 * 4 + r) * DIM);
  }
}

extern "C" void kernel_launch(void* const* d_in, const int* in_sizes, int n_in,
                              void* d_out, int out_size, void* d_ws, size_t ws_size,
                              hipStream_t stream) {
  const float* Q = (const float*)d_in[0];
  const float* K = (const float*)d_in[1];
  const float* V = (const float*)d_in[2];
  const float* s = (const float*)d_in[3];
  const float* G = (const float*)d_in[4];
  float* O = (float*)d_out;

  const size_t elems = (size_t)32 * LQ * DIM;           // per tensor
  const size_t need  = elems * 2 /*bf16*/ * 2 /*K+VT*/; // 16 MB
  if (ws_size >= need) {
    unsigned short* Kb = (unsigned short*)d_ws;
    unsigned short* VT = Kb + elems;
    prep_kv<<<256, NT, 0, stream>>>(K, V, Kb, VT);
    dsma_kernel<true><<<1024, NT, 0, stream>>>(Q, K, V, Kb, VT, s, G, O);
  } else {
    dsma_kernel<false><<<1024, NT, 0, stream>>>(Q, K, V, nullptr, nullptr, s, G, O);
  }
}